// Round 1
// baseline (44.654 us; speedup 1.0000x reference)
//
#include <hip/hip_runtime.h>
#include <hip/hip_bf16.h>

// GaussianVideo3D2D: N gaussians -> (T=4, H=128, W=128, C=3) fp32 volume.
// Strategy:
//   prep_kernel: per (n,t) fold means/Sinv/alpha/t into 6 quadratic coeffs
//                earg(x,y) = A x^2 + B y^2 + C xy + Dx x + Dy y + E
//                with -0.5*log2(e) and log2(alpha) pre-folded, so
//                dens = exp2f(earg). Stored as 3 float4 per (t*N+n) in d_ws.
//   splat_kernel: block = 512 thr = 8 waves; covers one 8x8 pixel tile at one
//                t. Waves split the N gaussians into 8 contiguous chunks
//                (wave-uniform addresses -> s_load), LDS-reduce partials.

#define GV_H 128
#define GV_W 128
#define GV_T 4
#define K_HALF_LOG2E (-0.72134752044448170f)  // -0.5 * log2(e)

__global__ __launch_bounds__(256) void gv_prep_kernel(
    const float* __restrict__ xyz, const float* __restrict__ chol,
    const float* __restrict__ feats, const float* __restrict__ opac,
    float4* __restrict__ table, int N)
{
    int i = blockIdx.x * blockDim.x + threadIdx.x;  // entry index = t*N + n
    int total = N * GV_T;
    if (i >= total) return;
    int t = i / N;
    int n = i - t * N;

    float mx = tanhf(xyz[n * 3 + 0]);
    float my = tanhf(xyz[n * 3 + 1]);
    float mt = tanhf(xyz[n * 3 + 2]);

    const float s = 2.0f * 16.0f / (float)GV_W;  // SCALE = 0.25
    float L00 = s * (chol[n * 6 + 0] + 0.5f);
    float L10 = s * (chol[n * 6 + 1]);
    float L20 = s * (chol[n * 6 + 2]);
    float L11 = s * (chol[n * 6 + 3] + 0.5f);
    float L21 = s * (chol[n * 6 + 4]);
    float L22 = s * (chol[n * 6 + 5] + 0.5f);

    // Sinv = Linv^T Linv, Linv analytic (L lower triangular)
    float il0 = 1.0f / L00, il1 = 1.0f / L11, il2 = 1.0f / L22;
    float m10 = -L10 * il0 * il1;
    float m21 = -L21 * il1 * il2;
    float m20 = (L10 * L21 - L11 * L20) * (il0 * il1 * il2);
    float a   = il0 * il0 + m10 * m10 + m20 * m20;  // Sinv00
    float sab = m10 * il1 + m20 * m21;              // Sinv01
    float sat = m20 * il2;                          // Sinv02
    float b   = il1 * il1 + m21 * m21;              // Sinv11
    float sbt = m21 * il2;                          // Sinv12
    float c   = il2 * il2;                          // Sinv22
    float ab2 = 2.0f * sab, at2 = 2.0f * sat, bt2 = 2.0f * sbt;

    float o = opac[n];
    float alpha = 1.0f / (1.0f + expf(-o));
    float bias = log2f(alpha);

    float tv = ((float)t + 0.5f) * (2.0f / (float)GV_T) - 1.0f;
    float dt = tv - mt;

    const float k = K_HALF_LOG2E;
    float A  = k * a;
    float B  = k * b;
    float C  = k * ab2;
    float Dx = k * (at2 * dt - 2.0f * a * mx - ab2 * my);
    float Dy = k * (bt2 * dt - 2.0f * b * my - ab2 * mx);
    float E  = k * (a * mx * mx + b * my * my + c * dt * dt
                    + ab2 * mx * my - at2 * mx * dt - bt2 * my * dt) + bias;

    float fr = feats[n * 3 + 0];
    float fg = feats[n * 3 + 1];
    float fb = feats[n * 3 + 2];

    table[(size_t)i * 3 + 0] = make_float4(A, B, C, Dx);
    table[(size_t)i * 3 + 1] = make_float4(Dy, E, fr, fg);
    table[(size_t)i * 3 + 2] = make_float4(fb, 0.0f, 0.0f, 0.0f);
}

__global__ __launch_bounds__(512) void gv_splat_kernel(
    const float4* __restrict__ table, float* __restrict__ out, int N)
{
    __shared__ float4 red[8][64];

    int b  = blockIdx.x;           // 0..1023: [t(2b) | th(4b) | tw(4b)]
    int tw = b & 15;
    int th = (b >> 4) & 15;
    int t  = b >> 8;

    int tid  = threadIdx.x;
    int wv   = __builtin_amdgcn_readfirstlane(tid >> 6);  // wave id, uniform
    int lane = tid & 63;
    int lx   = lane & 7;
    int ly   = lane >> 3;
    int w    = tw * 8 + lx;
    int h    = th * 8 + ly;

    float x  = ((float)w + 0.5f) * (2.0f / (float)GV_W) - 1.0f;
    float y  = ((float)h + 0.5f) * (2.0f / (float)GV_H) - 1.0f;
    float xx = x * x, yy = y * y, xy = x * y;

    int chunk = (N + 7) >> 3;
    int g0    = wv * chunk;
    int cnt   = N - g0;
    if (cnt > chunk) cnt = chunk;
    if (cnt < 0) cnt = 0;

    const float4* __restrict__ P =
        table + ((size_t)t * (size_t)N + (size_t)g0) * 3;

    float accr = 0.0f, accg = 0.0f, accb = 0.0f;

    #pragma unroll 4
    for (int i = 0; i < cnt; ++i) {
        float4 v0 = P[i * 3 + 0];  // A B C Dx
        float4 v1 = P[i * 3 + 1];  // Dy E fr fg
        float4 v2 = P[i * 3 + 2];  // fb - - -
        float e1 = fmaf(v0.x, xx, v1.y);
        e1 = fmaf(v0.y, yy, e1);
        e1 = fmaf(v0.z, xy, e1);
        e1 = fmaf(v0.w, x,  e1);
        e1 = fmaf(v1.x, y,  e1);
        float e = exp2f(e1);
        accr = fmaf(e, v1.z, accr);
        accg = fmaf(e, v1.w, accg);
        accb = fmaf(e, v2.x, accb);
    }

    red[wv][lane] = make_float4(accr, accg, accb, 0.0f);
    __syncthreads();

    if (wv == 0) {
        float4 acc = red[0][lane];
        #pragma unroll
        for (int k2 = 1; k2 < 8; ++k2) {
            float4 v = red[k2][lane];
            acc.x += v.x;
            acc.y += v.y;
            acc.z += v.z;
        }
        int idx = ((t * GV_H + h) * GV_W + w) * 3;
        out[idx + 0] = fminf(fmaxf(acc.x, 0.0f), 1.0f);
        out[idx + 1] = fminf(fmaxf(acc.y, 0.0f), 1.0f);
        out[idx + 2] = fminf(fmaxf(acc.z, 0.0f), 1.0f);
    }
}

extern "C" void kernel_launch(void* const* d_in, const int* in_sizes, int n_in,
                              void* d_out, int out_size, void* d_ws, size_t ws_size,
                              hipStream_t stream) {
    const float* xyz   = (const float*)d_in[0];
    const float* chol  = (const float*)d_in[1];
    const float* feats = (const float*)d_in[2];
    const float* opac  = (const float*)d_in[3];
    float* out = (float*)d_out;
    int N = in_sizes[0] / 3;

    float4* table = (float4*)d_ws;  // N*T*3 float4 = 192 KB for N=1024

    int total = N * GV_T;
    int pblocks = (total + 255) / 256;
    gv_prep_kernel<<<pblocks, 256, 0, stream>>>(xyz, chol, feats, opac, table, N);

    int sblocks = GV_T * (GV_H / 8) * (GV_W / 8);  // 1024
    gv_splat_kernel<<<sblocks, 512, 0, stream>>>(table, out, N);
}

// Round 2
// 34.760 us; speedup vs baseline: 1.2847x; 1.2847x over previous
//
#include <hip/hip_runtime.h>
#include <hip/hip_bf16.h>

// GaussianVideo3D2D: N gaussians -> (T=4, H=128, W=128, C=3) fp32 volume.
//   prep_kernel: per (n,t) fold means/Sinv/alpha/t into quadratic coeffs
//       earg(x,y) = A x^2 + B y^2 + C xy + Dx x + Dy y + E  (log2 domain)
//       dens = exp2(earg). SoA tables in d_ws: q0={A,B,C,Dx}, q1={Dy,E,fr,fg},
//       fb[] scalar.
//   splat_kernel: 512 thr (8 waves) per 8x8 pixel tile at one t. Block stages
//       its t-slice (36,864 B) into LDS with coalesced vector loads, then the
//       gaussian loop reads LDS broadcasts (ds_read_b128, in-order lgkmcnt ->
//       compiler software-pipelines). Waves split gaussians 8 ways; staging
//       LDS is reused for the cross-wave reduction. 36.9 KB -> 4 blocks/CU =
//       32 waves/CU.

#define GV_H 128
#define GV_W 128
#define GV_T 4
#define GV_NMAX 1024
#define K_HALF_LOG2E (-0.72134752044448170f)  // -0.5 * log2(e)

__global__ __launch_bounds__(256) void gv_prep_kernel(
    const float* __restrict__ xyz, const float* __restrict__ chol,
    const float* __restrict__ feats, const float* __restrict__ opac,
    float4* __restrict__ q0g, float4* __restrict__ q1g,
    float* __restrict__ fbg, int N)
{
    int i = blockIdx.x * blockDim.x + threadIdx.x;  // entry index = t*N + n
    int total = N * GV_T;
    if (i >= total) return;
    int t = i / N;
    int n = i - t * N;

    float mx = tanhf(xyz[n * 3 + 0]);
    float my = tanhf(xyz[n * 3 + 1]);
    float mt = tanhf(xyz[n * 3 + 2]);

    const float s = 2.0f * 16.0f / (float)GV_W;  // SCALE = 0.25
    float L00 = s * (chol[n * 6 + 0] + 0.5f);
    float L10 = s * (chol[n * 6 + 1]);
    float L20 = s * (chol[n * 6 + 2]);
    float L11 = s * (chol[n * 6 + 3] + 0.5f);
    float L21 = s * (chol[n * 6 + 4]);
    float L22 = s * (chol[n * 6 + 5] + 0.5f);

    // Sinv = Linv^T Linv, Linv analytic (L lower triangular)
    float il0 = 1.0f / L00, il1 = 1.0f / L11, il2 = 1.0f / L22;
    float m10 = -L10 * il0 * il1;
    float m21 = -L21 * il1 * il2;
    float m20 = (L10 * L21 - L11 * L20) * (il0 * il1 * il2);
    float a   = il0 * il0 + m10 * m10 + m20 * m20;  // Sinv00
    float sab = m10 * il1 + m20 * m21;              // Sinv01
    float sat = m20 * il2;                          // Sinv02
    float b   = il1 * il1 + m21 * m21;              // Sinv11
    float sbt = m21 * il2;                          // Sinv12
    float c   = il2 * il2;                          // Sinv22
    float ab2 = 2.0f * sab, at2 = 2.0f * sat, bt2 = 2.0f * sbt;

    float o = opac[n];
    float alpha = 1.0f / (1.0f + expf(-o));
    float bias = log2f(alpha);

    float tv = ((float)t + 0.5f) * (2.0f / (float)GV_T) - 1.0f;
    float dt = tv - mt;

    const float k = K_HALF_LOG2E;
    float A  = k * a;
    float B  = k * b;
    float C  = k * ab2;
    float Dx = k * (at2 * dt - 2.0f * a * mx - ab2 * my);
    float Dy = k * (bt2 * dt - 2.0f * b * my - ab2 * mx);
    float E  = k * (a * mx * mx + b * my * my + c * dt * dt
                    + ab2 * mx * my - at2 * mx * dt - bt2 * my * dt) + bias;

    float fr = feats[n * 3 + 0];
    float fg = feats[n * 3 + 1];
    float fb = feats[n * 3 + 2];

    q0g[i] = make_float4(A, B, C, Dx);
    q1g[i] = make_float4(Dy, E, fr, fg);
    fbg[i] = fb;
}

__global__ __launch_bounds__(512) void gv_splat_kernel(
    const float4* __restrict__ q0g, const float4* __restrict__ q1g,
    const float* __restrict__ fbg, float* __restrict__ out, int N)
{
    __shared__ float4 sq0[GV_NMAX];   // 16 KB
    __shared__ float4 sq1[GV_NMAX];   // 16 KB
    __shared__ float  sfb[GV_NMAX];   //  4 KB  -> 36,864 B total

    int b  = blockIdx.x;           // 0..1023: [t(2b) | th(4b) | tw(4b)]
    int tw = b & 15;
    int th = (b >> 4) & 15;
    int t  = b >> 8;

    int tid  = threadIdx.x;
    int wv   = __builtin_amdgcn_readfirstlane(tid >> 6);  // wave id, uniform
    int lane = tid & 63;
    int lx   = lane & 7;
    int ly   = lane >> 3;
    int w    = tw * 8 + lx;
    int h    = th * 8 + ly;

    // stage this t's slice into LDS (coalesced vector loads)
    {
        int base = t * N;
        for (int i = tid; i < N; i += 512) {
            sq0[i] = q0g[base + i];
            sq1[i] = q1g[base + i];
            sfb[i] = fbg[base + i];
        }
    }
    __syncthreads();

    float x  = ((float)w + 0.5f) * (2.0f / (float)GV_W) - 1.0f;
    float y  = ((float)h + 0.5f) * (2.0f / (float)GV_H) - 1.0f;
    float xx = x * x, yy = y * y, xy = x * y;

    int chunk = (N + 7) >> 3;
    int g0    = wv * chunk;
    int cnt   = N - g0;
    if (cnt > chunk) cnt = chunk;
    if (cnt < 0) cnt = 0;

    float accr = 0.0f, accg = 0.0f, accb = 0.0f;

    #pragma unroll 8
    for (int i = 0; i < cnt; ++i) {
        float4 v0 = sq0[g0 + i];   // A B C Dx
        float4 v1 = sq1[g0 + i];   // Dy E fr fg
        float  fb = sfb[g0 + i];   // fb
        float e1 = fmaf(v0.x, xx, v1.y);
        e1 = fmaf(v0.y, yy, e1);
        e1 = fmaf(v0.z, xy, e1);
        e1 = fmaf(v0.w, x,  e1);
        e1 = fmaf(v1.x, y,  e1);
        float e = exp2f(e1);
        accr = fmaf(e, v1.z, accr);
        accg = fmaf(e, v1.w, accg);
        accb = fmaf(e, fb,  accb);
    }

    // reuse staging LDS for the cross-wave reduction
    __syncthreads();
    float4* red = sq0;
    red[wv * 64 + lane] = make_float4(accr, accg, accb, 0.0f);
    __syncthreads();

    if (wv == 0) {
        float4 acc = red[lane];
        #pragma unroll
        for (int k2 = 1; k2 < 8; ++k2) {
            float4 v = red[k2 * 64 + lane];
            acc.x += v.x;
            acc.y += v.y;
            acc.z += v.z;
        }
        int idx = ((t * GV_H + h) * GV_W + w) * 3;
        out[idx + 0] = fminf(fmaxf(acc.x, 0.0f), 1.0f);
        out[idx + 1] = fminf(fmaxf(acc.y, 0.0f), 1.0f);
        out[idx + 2] = fminf(fmaxf(acc.z, 0.0f), 1.0f);
    }
}

extern "C" void kernel_launch(void* const* d_in, const int* in_sizes, int n_in,
                              void* d_out, int out_size, void* d_ws, size_t ws_size,
                              hipStream_t stream) {
    const float* xyz   = (const float*)d_in[0];
    const float* chol  = (const float*)d_in[1];
    const float* feats = (const float*)d_in[2];
    const float* opac  = (const float*)d_in[3];
    float* out = (float*)d_out;
    int N = in_sizes[0] / 3;

    char* ws = (char*)d_ws;
    float4* q0g = (float4*)ws;                                   // T*N*16 B
    float4* q1g = (float4*)(ws + (size_t)GV_T * N * 16);         // T*N*16 B
    float*  fbg = (float*) (ws + (size_t)GV_T * N * 32);         // T*N*4 B

    int total = N * GV_T;
    int pblocks = (total + 255) / 256;
    gv_prep_kernel<<<pblocks, 256, 0, stream>>>(xyz, chol, feats, opac,
                                                q0g, q1g, fbg, N);

    int sblocks = GV_T * (GV_H / 8) * (GV_W / 8);  // 1024
    gv_splat_kernel<<<sblocks, 512, 0, stream>>>(q0g, q1g, fbg, out, N);
}

// Round 3
// 29.620 us; speedup vs baseline: 1.5076x; 1.1735x over previous
//
#include <hip/hip_runtime.h>

// GaussianVideo3D2D: N gaussians -> (T=4, H=128, W=128, C=3) fp32 volume.
//
// prep: per (t,n) fold means/Sinv/alpha/t into a 12-dword record:
//   earg(x,y) = A x^2 + B y^2 + C xy + Dx x + Dy y + E   (log2 domain,
//   -0.5*log2e and log2(alpha) folded), dens = exp2(earg).
//   record = {A,B,C,Dx | Dy,E,s,fr | fg,fb,DxD,CD}
//   s  = exp2(2*A*DX^2)  : x-recurrence curvature ratio
//   DxD= Dx*DX, CD = C*DX: folded into r0 = exp2(A*cA + CD*y + DxD)
//
// splat: 256 blocks (64 two-row slabs x 4 t) x 1024 thr (16 waves).
//   Block stages its t-slice (48 KB) into LDS. Each wave = one 16-way
//   gaussian split; each lane owns a 4-px x-run (lx=lane&31 -> x-quad,
//   ly=lane>>5 -> row). Per gaussian: 3 x ds_read_b128 broadcast,
//   e0=exp2(earg(x0)), r0=exp2(delta), then e*=r, r*=s recurrence
//   -> 26 VALU + 2 trans + 3 DS per 4 (gaussian,pixel) pairs.
//   16-way cross-wave reduction via LDS, 256 threads write output.

#define GV_H 128
#define GV_W 128
#define GV_T 4
#define GV_NMAX 1024
#define GV_DX 0.015625f                       // 2/128
#define K_HALF_LOG2E (-0.72134752044448170f)  // -0.5 * log2(e)

__global__ __launch_bounds__(256) void gv_prep_kernel(
    const float* __restrict__ xyz, const float* __restrict__ chol,
    const float* __restrict__ feats, const float* __restrict__ opac,
    float4* __restrict__ table, int N)
{
    int i = blockIdx.x * blockDim.x + threadIdx.x;  // entry index = t*N + n
    int total = N * GV_T;
    if (i >= total) return;
    int t = i / N;
    int n = i - t * N;

    float mx = tanhf(xyz[n * 3 + 0]);
    float my = tanhf(xyz[n * 3 + 1]);
    float mt = tanhf(xyz[n * 3 + 2]);

    const float s = 2.0f * 16.0f / (float)GV_W;  // SCALE = 0.25
    float L00 = s * (chol[n * 6 + 0] + 0.5f);
    float L10 = s * (chol[n * 6 + 1]);
    float L20 = s * (chol[n * 6 + 2]);
    float L11 = s * (chol[n * 6 + 3] + 0.5f);
    float L21 = s * (chol[n * 6 + 4]);
    float L22 = s * (chol[n * 6 + 5] + 0.5f);

    // Sinv = Linv^T Linv, Linv analytic (L lower triangular)
    float il0 = 1.0f / L00, il1 = 1.0f / L11, il2 = 1.0f / L22;
    float m10 = -L10 * il0 * il1;
    float m21 = -L21 * il1 * il2;
    float m20 = (L10 * L21 - L11 * L20) * (il0 * il1 * il2);
    float a   = il0 * il0 + m10 * m10 + m20 * m20;  // Sinv00
    float sab = m10 * il1 + m20 * m21;              // Sinv01
    float sat = m20 * il2;                          // Sinv02
    float b   = il1 * il1 + m21 * m21;              // Sinv11
    float sbt = m21 * il2;                          // Sinv12
    float c   = il2 * il2;                          // Sinv22
    float ab2 = 2.0f * sab, at2 = 2.0f * sat, bt2 = 2.0f * sbt;

    float o = opac[n];
    float alpha = 1.0f / (1.0f + expf(-o));
    float bias = log2f(alpha);

    float tv = ((float)t + 0.5f) * (2.0f / (float)GV_T) - 1.0f;
    float dt = tv - mt;

    const float k = K_HALF_LOG2E;
    float A  = k * a;
    float B  = k * b;
    float C  = k * ab2;
    float Dx = k * (at2 * dt - 2.0f * a * mx - ab2 * my);
    float Dy = k * (bt2 * dt - 2.0f * b * my - ab2 * mx);
    float E  = k * (a * mx * mx + b * my * my + c * dt * dt
                    + ab2 * mx * my - at2 * mx * dt - bt2 * my * dt) + bias;

    float fr = feats[n * 3 + 0];
    float fg = feats[n * 3 + 1];
    float fb = feats[n * 3 + 2];

    float sx  = exp2f(2.0f * A * GV_DX * GV_DX);  // recurrence ratio-ratio
    float DxD = Dx * GV_DX;
    float CD  = C * GV_DX;

    table[(size_t)i * 3 + 0] = make_float4(A, B, C, Dx);
    table[(size_t)i * 3 + 1] = make_float4(Dy, E, sx, fr);
    table[(size_t)i * 3 + 2] = make_float4(fg, fb, DxD, CD);
}

__global__ __launch_bounds__(1024) void gv_splat_kernel(
    const float4* __restrict__ table, float* __restrict__ out, int N)
{
    __shared__ float  stab[GV_NMAX * 12];  // 48 KB staged records
    __shared__ float4 red4[1024 * 3];      // 48 KB partial sums

    int b    = blockIdx.x;   // 0..255: [t(2b) | slab(6b)]
    int slab = b & 63;
    int t    = b >> 6;

    int tid = threadIdx.x;

    // stage this t's 48 KB slice (coalesced float4)
    {
        const float4* src = table + (size_t)t * (size_t)N * 3;
        float4* dst = (float4*)stab;
        int nv = N * 3;
        for (int j = tid; j < nv; j += 1024) dst[j] = src[j];
    }
    __syncthreads();

    int wv   = tid >> 6;      // 0..15 : gaussian split
    int lane = tid & 63;
    int lx   = lane & 31;     // x-quad index (32 quads * 4 px = 128)
    int ly   = lane >> 5;     // row within slab
    int y_i  = slab * 2 + ly;

    float x0  = ((float)(lx * 4) + 0.5f) * GV_DX - 1.0f;
    float y   = ((float)y_i + 0.5f) * GV_DX - 1.0f;
    float xx0 = x0 * x0, x0y = x0 * y, yy = y * y;
    float cA  = GV_DX * (2.0f * x0 + GV_DX);

    int chunk = (N + 15) >> 4;
    int g0    = wv * chunk;
    int cnt   = N - g0;
    if (cnt > chunk) cnt = chunk;
    if (cnt < 0) cnt = 0;

    float a00 = 0.f, a01 = 0.f, a02 = 0.f;
    float a10 = 0.f, a11 = 0.f, a12 = 0.f;
    float a20 = 0.f, a21 = 0.f, a22 = 0.f;
    float a30 = 0.f, a31 = 0.f, a32 = 0.f;

    const float* sp = &stab[g0 * 12];

    #pragma unroll 4
    for (int i = 0; i < cnt; ++i) {
        const float4* q = (const float4*)(sp + i * 12);
        float4 v0 = q[0];  // A B C Dx
        float4 v1 = q[1];  // Dy E s fr
        float4 v2 = q[2];  // fg fb DxD CD
        float u = fmaf(v0.x, xx0,
                  fmaf(v0.y, yy,
                  fmaf(v0.z, x0y,
                  fmaf(v0.w, x0,
                  fmaf(v1.x, y, v1.y)))));
        float e = exp2f(u);
        float r = exp2f(fmaf(v0.x, cA, fmaf(v2.w, y, v2.z)));
        float s = v1.z;
        a00 = fmaf(e, v1.w, a00);
        a01 = fmaf(e, v2.x, a01);
        a02 = fmaf(e, v2.y, a02);
        e *= r; r *= s;
        a10 = fmaf(e, v1.w, a10);
        a11 = fmaf(e, v2.x, a11);
        a12 = fmaf(e, v2.y, a12);
        e *= r; r *= s;
        a20 = fmaf(e, v1.w, a20);
        a21 = fmaf(e, v2.x, a21);
        a22 = fmaf(e, v2.y, a22);
        e *= r;
        a30 = fmaf(e, v1.w, a30);
        a31 = fmaf(e, v2.x, a31);
        a32 = fmaf(e, v2.y, a32);
    }

    // dump partials (3 x float4 per thread)
    red4[tid * 3 + 0] = make_float4(a00, a01, a02, a10);
    red4[tid * 3 + 1] = make_float4(a11, a12, a20, a21);
    red4[tid * 3 + 2] = make_float4(a22, a30, a31, a32);
    __syncthreads();

    // 16-way cross-wave reduction; 256 threads, one pixel each
    if (tid < 256) {
        int x2    = tid & 127;
        int ly2   = tid >> 7;
        int lslot = ly2 * 32 + (x2 >> 2);
        int poff  = (x2 & 3) * 3;
        const float* rp = (const float*)red4;
        float s0 = 0.f, s1 = 0.f, s2 = 0.f;
        #pragma unroll
        for (int sIdx = 0; sIdx < 16; ++sIdx) {
            const float* p = rp + (sIdx * 64 + lslot) * 12 + poff;
            s0 += p[0];
            s1 += p[1];
            s2 += p[2];
        }
        int y_o = slab * 2 + ly2;
        int idx = ((t * GV_H + y_o) * GV_W + x2) * 3;
        out[idx + 0] = fminf(fmaxf(s0, 0.0f), 1.0f);
        out[idx + 1] = fminf(fmaxf(s1, 0.0f), 1.0f);
        out[idx + 2] = fminf(fmaxf(s2, 0.0f), 1.0f);
    }
}

extern "C" void kernel_launch(void* const* d_in, const int* in_sizes, int n_in,
                              void* d_out, int out_size, void* d_ws, size_t ws_size,
                              hipStream_t stream) {
    const float* xyz   = (const float*)d_in[0];
    const float* chol  = (const float*)d_in[1];
    const float* feats = (const float*)d_in[2];
    const float* opac  = (const float*)d_in[3];
    float* out = (float*)d_out;
    int N = in_sizes[0] / 3;
    if (N > GV_NMAX) N = GV_NMAX;  // LDS staging capacity (reference N=1024)

    float4* table = (float4*)d_ws;  // T*N*48 B = 192 KB

    int total = N * GV_T;
    int pblocks = (total + 255) / 256;
    gv_prep_kernel<<<pblocks, 256, 0, stream>>>(xyz, chol, feats, opac, table, N);

    int sblocks = GV_T * (GV_H / 2);  // 256: 64 slabs x 4 t
    gv_splat_kernel<<<sblocks, 1024, 0, stream>>>(table, out, N);
}

// Round 4
// 21.937 us; speedup vs baseline: 2.0355x; 1.3502x over previous
//
#include <hip/hip_runtime.h>

// GaussianVideo3D2D: N gaussians -> (T=4, H=128, W=128, C=3) fp32 volume.
// Single fused kernel, 256 blocks (64 two-row slabs x 4 t) x 1024 thr (16 waves).
//
// Phase 1 (prep, fused): thread n computes gaussian n's record for this
//   block's t directly into LDS:
//     earg(x,y) = A x^2 + B y^2 + C xy + Dx x + Dy y + E  (log2 domain,
//     -0.5*log2e and log2(alpha) folded), dens = exp2(earg)
//     record = {A,B,C,Dx | Dy,E,s,fr | fg,fb,DxD,CD}, s=exp2(2A*DX^2),
//     DxD=Dx*DX, CD=C*DX (for the x-recurrence ratio r).
//
// Phase 2 (splat): wave lane layout: oct=lane&15 (8-px x-run), row=(lane>>4)&1,
//   half=lane>>5. Each wave owns a 16-way gaussian chunk; its two halves take
//   alternating gaussians (2-address LDS broadcast = free). Per gaussian:
//   3 x ds_read_b128, e0=exp2(u), r0=exp2(.), then e*=r, r*=s recurrence over
//   8 px -> ~44 VALU + 2 trans + 3 DS per 512 (gaussian,pixel) pairs/wave.
//
// Phase 3 (reduce): cross-half shfl_xor(32) in regs, dump 16 wave-partials
//   (48 KB, reusing record LDS), final sum with LDS offset == tid
//   (conflict-free), coalesced 768-float contiguous output per block.

#define GV_H 128
#define GV_W 128
#define GV_T 4
#define GV_NMAX 1024
#define GV_DX 0.015625f                       // 2/128
#define K_HALF_LOG2E (-0.72134752044448170f)  // -0.5 * log2(e)

__global__ __launch_bounds__(1024) void gv_fused_kernel(
    const float* __restrict__ xyz, const float* __restrict__ chol,
    const float* __restrict__ feats, const float* __restrict__ opac,
    float* __restrict__ out, int N)
{
    __shared__ float stab[GV_NMAX * 12];  // 48 KB: records, then partials

    int b    = blockIdx.x;   // 0..255: [t(2b) | slab(6b)]
    int slab = b & 63;
    int t    = b >> 6;
    int tid  = threadIdx.x;

    // ---------------- Phase 1: fused prep (1 record / thread) --------------
    if (tid < N) {
        int n = tid;
        float mx = tanhf(xyz[n * 3 + 0]);
        float my = tanhf(xyz[n * 3 + 1]);
        float mt = tanhf(xyz[n * 3 + 2]);

        const float sc = 2.0f * 16.0f / (float)GV_W;  // SCALE = 0.25
        float L00 = sc * (chol[n * 6 + 0] + 0.5f);
        float L10 = sc * (chol[n * 6 + 1]);
        float L20 = sc * (chol[n * 6 + 2]);
        float L11 = sc * (chol[n * 6 + 3] + 0.5f);
        float L21 = sc * (chol[n * 6 + 4]);
        float L22 = sc * (chol[n * 6 + 5] + 0.5f);

        float il0 = 1.0f / L00, il1 = 1.0f / L11, il2 = 1.0f / L22;
        float m10 = -L10 * il0 * il1;
        float m21 = -L21 * il1 * il2;
        float m20 = (L10 * L21 - L11 * L20) * (il0 * il1 * il2);
        float a   = il0 * il0 + m10 * m10 + m20 * m20;  // Sinv00
        float sab = m10 * il1 + m20 * m21;              // Sinv01
        float sat = m20 * il2;                          // Sinv02
        float bb  = il1 * il1 + m21 * m21;              // Sinv11
        float sbt = m21 * il2;                          // Sinv12
        float cc  = il2 * il2;                          // Sinv22
        float ab2 = 2.0f * sab, at2 = 2.0f * sat, bt2 = 2.0f * sbt;

        float o = opac[n];
        float alpha = 1.0f / (1.0f + expf(-o));
        float bias = log2f(alpha);

        float tv = ((float)t + 0.5f) * (2.0f / (float)GV_T) - 1.0f;
        float dt = tv - mt;

        const float k = K_HALF_LOG2E;
        float A  = k * a;
        float B  = k * bb;
        float C  = k * ab2;
        float Dx = k * (at2 * dt - 2.0f * a * mx - ab2 * my);
        float Dy = k * (bt2 * dt - 2.0f * bb * my - ab2 * mx);
        float E  = k * (a * mx * mx + bb * my * my + cc * dt * dt
                        + ab2 * mx * my - at2 * mx * dt - bt2 * my * dt) + bias;

        float fr = feats[n * 3 + 0];
        float fg = feats[n * 3 + 1];
        float fb = feats[n * 3 + 2];

        float sx  = exp2f(2.0f * A * GV_DX * GV_DX);
        float DxD = Dx * GV_DX;
        float CD  = C * GV_DX;

        float4* rec = (float4*)&stab[n * 12];
        rec[0] = make_float4(A, B, C, Dx);
        rec[1] = make_float4(Dy, E, sx, fr);
        rec[2] = make_float4(fg, fb, DxD, CD);
    }
    __syncthreads();

    // ---------------- Phase 2: splat ---------------------------------------
    int wv   = tid >> 6;          // 0..15 : gaussian 16-way split
    int lane = tid & 63;
    int oct  = lane & 15;         // 8-px x-run
    int row  = (lane >> 4) & 1;   // row within 2-row slab
    int half = lane >> 5;         // gaussian parity within wave's chunk
    int y_i  = slab * 2 + row;

    float x0  = ((float)(oct * 8) + 0.5f) * GV_DX - 1.0f;
    float y   = ((float)y_i + 0.5f) * GV_DX - 1.0f;
    float xx0 = x0 * x0, x0y = x0 * y, yy = y * y;
    float cA  = GV_DX * (2.0f * x0 + GV_DX);

    int chunk = (N + 15) >> 4;
    int g0    = wv * chunk;
    int cnt   = N - g0;
    if (cnt > chunk) cnt = chunk;
    if (cnt < 0) cnt = 0;

    float aR[8], aG[8], aB[8];
    #pragma unroll
    for (int j = 0; j < 8; ++j) { aR[j] = 0.f; aG[j] = 0.f; aB[j] = 0.f; }

    #pragma unroll 2
    for (int i = half; i < cnt; i += 2) {
        const float4* q = (const float4*)&stab[(g0 + i) * 12];
        float4 v0 = q[0];  // A B C Dx
        float4 v1 = q[1];  // Dy E s fr
        float4 v2 = q[2];  // fg fb DxD CD
        float u = fmaf(v0.x, xx0,
                  fmaf(v0.y, yy,
                  fmaf(v0.z, x0y,
                  fmaf(v0.w, x0,
                  fmaf(v1.x, y, v1.y)))));
        float e = exp2f(u);
        float r = exp2f(fmaf(v0.x, cA, fmaf(v2.w, y, v2.z)));
        float s = v1.z;
        #pragma unroll
        for (int j = 0; j < 8; ++j) {
            aR[j] = fmaf(e, v1.w, aR[j]);
            aG[j] = fmaf(e, v2.x, aG[j]);
            aB[j] = fmaf(e, v2.y, aB[j]);
            if (j < 7) { e *= r; r *= s; }
        }
    }

    // ---------------- Phase 3: reduce --------------------------------------
    // cross-half combine in registers (lane ^ 32)
    #pragma unroll
    for (int j = 0; j < 8; ++j) {
        aR[j] += __shfl_xor(aR[j], 32, 64);
        aG[j] += __shfl_xor(aG[j], 32, 64);
        aB[j] += __shfl_xor(aB[j], 32, 64);
    }

    __syncthreads();  // main-loop LDS reads done; reuse stab for partials

    if (half == 0) {
        // lane = row*16 + oct in [0,32); layout: [wv][lane][j*3+c]
        float* dst = &stab[(wv * 32 + lane) * 24];
        #pragma unroll
        for (int j = 0; j < 8; ++j) {
            dst[j * 3 + 0] = aR[j];
            dst[j * 3 + 1] = aG[j];
            dst[j * 3 + 2] = aB[j];
        }
    }
    __syncthreads();

    // final: LDS offset == tid  (row*384 + x*3 + c == tid), conflict-free;
    // output block is 768 contiguous floats -> coalesced.
    if (tid < 2 * GV_W * 3) {
        float s0 = 0.f;
        #pragma unroll
        for (int wvI = 0; wvI < 16; ++wvI) s0 += stab[wvI * 768 + tid];
        int base = ((t * GV_H + slab * 2) * GV_W) * 3;
        out[base + tid] = fminf(fmaxf(s0, 0.0f), 1.0f);
    }
}

extern "C" void kernel_launch(void* const* d_in, const int* in_sizes, int n_in,
                              void* d_out, int out_size, void* d_ws, size_t ws_size,
                              hipStream_t stream) {
    const float* xyz   = (const float*)d_in[0];
    const float* chol  = (const float*)d_in[1];
    const float* feats = (const float*)d_in[2];
    const float* opac  = (const float*)d_in[3];
    float* out = (float*)d_out;
    int N = in_sizes[0] / 3;
    if (N > GV_NMAX) N = GV_NMAX;  // LDS record capacity (reference N=1024)

    int sblocks = GV_T * (GV_H / 2);  // 256: 64 slabs x 4 t
    gv_fused_kernel<<<sblocks, 1024, 0, stream>>>(xyz, chol, feats, opac, out, N);
}